// Round 1
// baseline (576.904 us; speedup 1.0000x reference)
//
#include <hip/hip_runtime.h>

#define N_NODES 100000
#define N_EDGES 1600000
#define IN_CH   64
#define HID_CH  64
#define OUT_CH  128
#define TILE    128
#define N_TILES (N_EDGES / TILE)   // 12500 exactly

typedef __attribute__((ext_vector_type(8))) __bf16    bf16x8;
typedef __attribute__((ext_vector_type(4))) float     f32x4;
typedef __attribute__((ext_vector_type(2))) _Float16  f16x2;
typedef __attribute__((ext_vector_type(8))) _Float16  f16x8;

__device__ __forceinline__ unsigned short f2bf(float f) {
    union { float f; unsigned int i; } c;
    c.f = f;
    unsigned int u = c.i;
    unsigned int r = (u + 0x7FFFu + ((u >> 16) & 1u)) >> 16;   // RNE
    return (unsigned short)r;
}

// packed fp16 atomic add (global_atomic_pk_add_f16, gfx90a+)
__device__ __forceinline__ void atomic_pk_add_f16(unsigned int* addr, f16x2 val) {
    typedef __attribute__((address_space(1))) f16x2 gf16x2;
    __builtin_amdgcn_global_atomic_fadd_v2f16((gf16x2*)(void*)addr, val);
}

// fused prep: x fp32->bf16 convert + node-type byte table + zero hsum/cnt.
__global__ void gnn_prep(const float* __restrict__ xf,
                         unsigned short* __restrict__ xb,
                         unsigned char* __restrict__ ntype,  // [N_NODES]
                         uint4* __restrict__ hz,      // hsum as uint4 (800k)
                         float4* __restrict__ cz) {   // cnt  as float4 (25k)
    int i = blockIdx.x * blockDim.x + threadIdx.x;
    if (i < 1600000) {
        float4 v = reinterpret_cast<const float4*>(xf)[i];
        ushort4 o;
        o.x = f2bf(v.x); o.y = f2bf(v.y); o.z = f2bf(v.z); o.w = f2bf(v.w);
        reinterpret_cast<ushort4*>(xb)[i] = o;
        if ((i & 15) == 0) {   // this vec4 holds cols 0..3 of node i/16
            int n = i >> 4;
            ntype[n] = (v.x == 0.0f) ? 0 : ((v.x == 1.0f) ? 1 : 2);
        }
    } else if (i < 2400000) {
        hz[i - 1600000] = (uint4){0u, 0u, 0u, 0u};
    } else if (i < 2425000) {
        cz[i - 2400000] = (float4){0.f, 0.f, 0.f, 0.f};
    }
}

// Edge kernel: h_e = relu([x_dst|x_src|ea] @ W1 + b1); masked scatter of the
// 64-ch hidden into hsum[dst] as PACKED fp16 atomics (2 ch/dword), zero-skip.
//
// BARRIER-FREE main loop: each wave owns a disjoint 32-edge slice of the tile
// and a disjoint LDS slice, so no __syncthreads is needed after weight
// staging. This avoids the s_waitcnt vmcnt(0) drain before s_barrier that
// serialized gather+atomic latency per tile (MfmaUtil was 6%, all pipes idle).
//
// Masked-out edges (~40%) redirect BOTH xb gathers to node 0 (L1-hot) — their
// MFMA rows are discarded in the epilogue anyway. Cuts random-gather FETCH.
//
// LDS diet (19968B -> 8 blocks/CU): w1tail folded into W1T cols 128..135 as
// one float4 per row {W1[128][n],W1[129][n],W1[130][n],b1[n]}; mask packed
// into dsts sign bit (dstm=0 means masked-out); eas stored as 3 floats.
__global__ __launch_bounds__(256, 8) void gnn_edge_hidden(
    const unsigned char*  __restrict__ ntype, // [N_NODES] node type 0/1/2
    const unsigned short* __restrict__ xb,    // [N_NODES][64] bf16 bits
    const int*            __restrict__ eidx,  // [2][N_EDGES]
    const float*          __restrict__ ea,    // [N_EDGES][3]
    const float*          __restrict__ W1,    // [131][64]
    const float*          __restrict__ b1,    // [64]
    unsigned int*         __restrict__ hsum,  // [N_NODES][32] packed-f16 pairs
    float*                __restrict__ cnt)   // [N_NODES] masked-edge counts
{
    __shared__ __align__(16) unsigned short W1T[64][136];   // [n][k] k<128 bf16; k=128..135: float4 tail
    __shared__ float eas[128][3];
    __shared__ int   dstm[128];   // dst | 0x80000000 if masked-in; 0 if masked-out
    __shared__ int   srcs[128];   // src (0 if masked-out)

    const int tid  = threadIdx.x;
    const int wave = tid >> 6;
    const int lane = tid & 63;
    const int q    = lane >> 4;   // quad 0..3
    const int m16  = lane & 15;

    // ---- stage W1 once per persistent block (fp32 -> bf16) ----
    for (int idx = tid; idx < 128 * 64; idx += 256) {
        int k = idx >> 6, n = idx & 63;
        W1T[n][k] = f2bf(W1[idx]);
    }
    if (tid < 64) {
        float4 tl;
        tl.x = W1[128 * 64 + tid];
        tl.y = W1[129 * 64 + tid];
        tl.z = W1[130 * 64 + tid];
        tl.w = b1[tid];
        *reinterpret_cast<float4*>(&W1T[tid][128]) = tl;   // row*272+256: 16B aligned
    }
    __syncthreads();   // the ONLY block barrier

    const int ebase = wave * 32;

    for (int t = blockIdx.x; t < N_TILES; t += gridDim.x) {
        // ---- per-wave staging: lanes 0..31 stage this wave's 32 edges ----
        // (in-wave LDS ordering: compiler lgkmcnt handles write->read; LDS pipe
        //  is in-order per wave so the cross-iteration WAR is also safe)
        if (lane < 32) {
            int e  = t * TILE + ebase + lane;
            int el = ebase + lane;
            int s = eidx[e];
            int d = eidx[N_EDGES + e];
            float a0 = ea[e * 3 + 0];
            float a1 = ea[e * 3 + 1];
            float a2 = ea[e * 3 + 2];
            eas[el][0] = a0; eas[el][1] = a1; eas[el][2] = a2;
            int ntc = ntype[s];   // 1-byte type, L2-resident table
            bool mk = (ntc == 0) ? (a0 < 0.5f) : ((ntc == 1) ? (a0 < 0.3f) : true);
            dstm[el] = mk ? (int)(0x80000000u | (unsigned)d) : 0;
            srcs[el] = mk ? s : 0;   // masked-out: gather node 0 (L1-hot)
            if (mk) unsafeAtomicAdd(&cnt[d], 1.0f);
        }

        // ---- acc init: b1 + ea @ W1[128:131] (fp32 VALU) ----
        f32x4 acc1[2][4];
#pragma unroll
        for (int mt = 0; mt < 2; ++mt) {
            float e0[4], e1[4], e2[4];
#pragma unroll
            for (int r = 0; r < 4; ++r) {
                int el = ebase + mt * 16 + q * 4 + r;   // C-layout row
                e0[r] = eas[el][0]; e1[r] = eas[el][1]; e2[r] = eas[el][2];
            }
#pragma unroll
            for (int nt = 0; nt < 4; ++nt) {
                int n = nt * 16 + m16;                  // C-layout col
                float4 wt = *reinterpret_cast<const float4*>(&W1T[n][128]);
#pragma unroll
                for (int r = 0; r < 4; ++r)
                    acc1[mt][nt][r] = wt.w + e0[r] * wt.x + e1[r] * wt.y + e2[r] * wt.z;
            }
        }

        // K=128 over [x_dst (kc 0,1) | x_src (kc 2,3)], A-frags from global bf16
#pragma unroll
        for (int kc = 0; kc < 4; ++kc) {
            bf16x8 af[2];
#pragma unroll
            for (int mt = 0; mt < 2; ++mt) {
                int el = ebase + mt * 16 + m16;         // A-layout row m=lane&15
                int dm = dstm[el];
                int node = (kc < 2) ? (dm & 0x7FFFFFFF) : srcs[el];
                af[mt] = *reinterpret_cast<const bf16x8*>(
                    xb + (size_t)node * IN_CH + (kc & 1) * 32 + q * 8);
            }
            __builtin_amdgcn_s_setprio(1);
#pragma unroll
            for (int nt = 0; nt < 4; ++nt) {
                bf16x8 bfr = *reinterpret_cast<const bf16x8*>(
                    &W1T[nt * 16 + m16][kc * 32 + q * 8]);
                acc1[0][nt] = __builtin_amdgcn_mfma_f32_16x16x32_bf16(af[0], bfr, acc1[0][nt], 0, 0, 0);
                acc1[1][nt] = __builtin_amdgcn_mfma_f32_16x16x32_bf16(af[1], bfr, acc1[1][nt], 0, 0, 0);
            }
            __builtin_amdgcn_s_setprio(0);
        }

        // ---- epilogue: masked relu(h) -> packed fp16 atomics, zero-skip ----
#pragma unroll
        for (int mt = 0; mt < 2; ++mt) {
#pragma unroll
            for (int r = 0; r < 4; ++r) {
                int el = ebase + mt * 16 + q * 4 + r;   // C-layout row
                int dm = dstm[el];
                if (dm < 0) {   // masked-in
                    unsigned int* hbase = hsum + (size_t)(dm & 0x7FFFFFFF) * 32;
                    float v0 = acc1[mt][0][r]; v0 = v0 > 0.f ? v0 : 0.f;
                    float v1 = acc1[mt][1][r]; v1 = v1 > 0.f ? v1 : 0.f;
                    float v2 = acc1[mt][2][r]; v2 = v2 > 0.f ? v2 : 0.f;
                    float v3 = acc1[mt][3][r]; v3 = v3 > 0.f ? v3 : 0.f;
                    if (v0 + v1 > 0.f) {   // pair (m16, m16+16) -> dword m16
                        f16x2 p01 = {(_Float16)v0, (_Float16)v1};
                        atomic_pk_add_f16(hbase + m16, p01);
                    }
                    if (v2 + v3 > 0.f) {   // pair (m16+32, m16+48) -> dword 16+m16
                        f16x2 p23 = {(_Float16)v2, (_Float16)v3};
                        atomic_pk_add_f16(hbase + 16 + m16, p23);
                    }
                }
            }
        }
    }
}

// Node kernel (MFMA): out[n] = relu(hsum[n] @ W2 + cnt[n]*b2).
// hsum is fp16 in permuted channel order pi(p); W2's rows are staged with the
// same permutation so the GEMM is oblivious to it.
__global__ __launch_bounds__(256, 4) void gnn_node_out(
    const _Float16* __restrict__ hsum,  // [N_NODES][64] fp16, permuted channels
    const float*    __restrict__ cnt,   // [N_NODES]
    const float*    __restrict__ W2,    // [64][128]
    const float*    __restrict__ b2,    // [128]
    float*          __restrict__ out)   // [N_NODES][128]
{
    __shared__ __align__(16) unsigned short W2T[128][72];  // W2T[n][p]=W2[pi(p)][n]
    __shared__ float b2s[128];

    const int tid  = threadIdx.x;
    const int wave = tid >> 6;
    const int lane = tid & 63;
    const int q    = lane >> 4;
    const int m16  = lane & 15;

    for (int idx = tid; idx < 64 * 128; idx += 256) {
        int p = idx >> 7, n = idx & 127;
        // pi(p): dword d=p>>1, half e=p&1; d<16 -> ch d+16e; d>=16 -> ch d+16+16e
        int ch = (p >> 1) + 16 * (p & 1) + ((p >= 32) ? 16 : 0);
        W2T[n][p] = f2bf(W2[ch * 128 + n]);
    }
    if (tid < 128) b2s[tid] = b2[tid];
    __syncthreads();

    const int nodeBase = (blockIdx.x * 4 + wave) * 32;
    if (nodeBase >= N_NODES) return;   // tail waves (no barriers below)

    f32x4 acc[2][8];
#pragma unroll
    for (int mt = 0; mt < 2; ++mt)
#pragma unroll
        for (int nt = 0; nt < 8; ++nt)
            acc[mt][nt] = (f32x4){0.0f, 0.0f, 0.0f, 0.0f};

#pragma unroll
    for (int kc = 0; kc < 2; ++kc) {
        bf16x8 af[2];
#pragma unroll
        for (int mt = 0; mt < 2; ++mt) {
            int node = nodeBase + mt * 16 + m16;       // A-layout row
            if (node >= N_NODES) node = N_NODES - 1;   // clamp; rows unused
            f16x8 h = *reinterpret_cast<const f16x8*>(
                hsum + (size_t)node * HID_CH + kc * 32 + q * 8);
            union { bf16x8 v; unsigned short u[8]; } rr;
#pragma unroll
            for (int j = 0; j < 8; ++j) rr.u[j] = f2bf((float)h[j]);
            af[mt] = rr.v;
        }
#pragma unroll
        for (int nt = 0; nt < 8; ++nt) {
            bf16x8 bfr = *reinterpret_cast<const bf16x8*>(
                &W2T[nt * 16 + m16][kc * 32 + q * 8]);
            acc[0][nt] = __builtin_amdgcn_mfma_f32_16x16x32_bf16(af[0], bfr, acc[0][nt], 0, 0, 0);
            acc[1][nt] = __builtin_amdgcn_mfma_f32_16x16x32_bf16(af[1], bfr, acc[1][nt], 0, 0, 0);
        }
    }

    // epilogue: + cnt*b2, relu, store (C-layout: row=q*4+r, col=nt*16+m16)
#pragma unroll
    for (int mt = 0; mt < 2; ++mt) {
        float cc[4]; int nn[4];
#pragma unroll
        for (int r = 0; r < 4; ++r) {
            nn[r] = nodeBase + mt * 16 + q * 4 + r;
            cc[r] = (nn[r] < N_NODES) ? cnt[nn[r]] : 0.0f;
        }
#pragma unroll
        for (int nt = 0; nt < 8; ++nt) {
            int col = nt * 16 + m16;
            float bb = b2s[col];
#pragma unroll
            for (int r = 0; r < 4; ++r) {
                if (nn[r] < N_NODES) {
                    float v = acc[mt][nt][r] + cc[r] * bb;
                    out[(size_t)nn[r] * OUT_CH + col] = v > 0.0f ? v : 0.0f;
                }
            }
        }
    }
}

extern "C" void kernel_launch(void* const* d_in, const int* in_sizes, int n_in,
                              void* d_out, int out_size, void* d_ws, size_t ws_size,
                              hipStream_t stream) {
    const float* x  = (const float*)d_in[0];
    const int*   ei = (const int*)d_in[1];
    const float* ea = (const float*)d_in[2];
    const float* W1 = (const float*)d_in[3];
    const float* b1 = (const float*)d_in[4];
    const float* W2 = (const float*)d_in[5];
    const float* b2 = (const float*)d_in[6];
    float* out = (float*)d_out;

    // ws layout: [hsum fp16 12.8MB][cnt 0.4MB][xb bf16 12.8MB][ntype 0.1MB]
    char* wsb = (char*)d_ws;
    unsigned int*   hsum  = (unsigned int*)wsb;                   // packed pairs
    float*          cnt   = (float*)(wsb + 12800000);
    unsigned short* xb    = (unsigned short*)(wsb + 13200000);
    unsigned char*  ntype = (unsigned char*)(wsb + 26000000);

    // fused prep: x->bf16 + node-type table + zero hsum/cnt
    gnn_prep<<<(2425000 + 255) / 256, 256, 0, stream>>>(
        x, xb, ntype, (uint4*)hsum, (float4*)cnt);

    // 2048 blocks = 8 blocks/CU (19968B LDS), barrier-free persistent loop
    gnn_edge_hidden<<<2048, 256, 0, stream>>>(ntype, xb, ei, ea, W1, b1, hsum, cnt);

    // node-level layer 2 + relu via MFMA: 128 nodes/block, 782 blocks
    gnn_node_out<<<(N_NODES + 127) / 128, 256, 0, stream>>>(
        (const _Float16*)hsum, cnt, W2, b2, out);
}

// Round 2
// 322.958 us; speedup vs baseline: 1.7863x; 1.7863x over previous
//
#include <hip/hip_runtime.h>

#define N_NODES 100000
#define N_EDGES 1600000
#define IN_CH   64
#define HID_CH  64
#define OUT_CH  128
#define TILE    128
#define N_TILES (N_EDGES / TILE)   // 12500 exactly

typedef __attribute__((ext_vector_type(8))) __bf16    bf16x8;
typedef __attribute__((ext_vector_type(4))) float     f32x4;
typedef __attribute__((ext_vector_type(2))) _Float16  f16x2;
typedef __attribute__((ext_vector_type(8))) _Float16  f16x8;

__device__ __forceinline__ unsigned short f2bf(float f) {
    union { float f; unsigned int i; } c;
    c.f = f;
    unsigned int u = c.i;
    unsigned int r = (u + 0x7FFFu + ((u >> 16) & 1u)) >> 16;   // RNE
    return (unsigned short)r;
}

// packed fp16 atomic add (global_atomic_pk_add_f16, gfx90a+)
__device__ __forceinline__ void atomic_pk_add_f16(unsigned int* addr, f16x2 val) {
    typedef __attribute__((address_space(1))) f16x2 gf16x2;
    __builtin_amdgcn_global_atomic_fadd_v2f16((gf16x2*)(void*)addr, val);
}

// fused prep: x fp32->bf16 convert + node-type byte table + zero hsum/cnt.
__global__ void gnn_prep(const float* __restrict__ xf,
                         unsigned short* __restrict__ xb,
                         unsigned char* __restrict__ ntype,  // [N_NODES]
                         uint4* __restrict__ hz,      // hsum as uint4 (800k)
                         float4* __restrict__ cz) {   // cnt  as float4 (25k)
    int i = blockIdx.x * blockDim.x + threadIdx.x;
    if (i < 1600000) {
        float4 v = reinterpret_cast<const float4*>(xf)[i];
        ushort4 o;
        o.x = f2bf(v.x); o.y = f2bf(v.y); o.z = f2bf(v.z); o.w = f2bf(v.w);
        reinterpret_cast<ushort4*>(xb)[i] = o;
        if ((i & 15) == 0) {   // this vec4 holds cols 0..3 of node i/16
            int n = i >> 4;
            ntype[n] = (v.x == 0.0f) ? 0 : ((v.x == 1.0f) ? 1 : 2);
        }
    } else if (i < 2400000) {
        hz[i - 1600000] = (uint4){0u, 0u, 0u, 0u};
    } else if (i < 2425000) {
        cz[i - 2400000] = (float4){0.f, 0.f, 0.f, 0.f};
    }
}

// Edge kernel: h_e = relu([x_dst|x_src|ea] @ W1 + b1); masked scatter of the
// 64-ch hidden into hsum[dst] as PACKED fp16 atomics (2 ch/dword), zero-skip.
//
// BARRIER-FREE main loop: each wave owns a disjoint 32-edge slice of the tile
// and a disjoint LDS slice, so no __syncthreads is needed after weight
// staging (in-order per-wave LDS pipe makes the cross-iteration WAR safe).
//
// Masked-out edges (~40%) redirect BOTH xb gathers to node 0 (L1-hot) — their
// MFMA rows are discarded in the epilogue anyway.
//
// __launch_bounds__(256, 4): round-1's (256,8) capped VGPR at 64 and the
// allocator landed at 32 -> the 32-reg accumulator spilled to scratch
// (FETCH 162->903MB, WRITE 150->569MB, 3x slower). (256,4) gives the
// allocator 128; the body needs ~60, which still permits 8 blocks/CU in HW.
__global__ __launch_bounds__(256, 4) void gnn_edge_hidden(
    const unsigned char*  __restrict__ ntype, // [N_NODES] node type 0/1/2
    const unsigned short* __restrict__ xb,    // [N_NODES][64] bf16 bits
    const int*            __restrict__ eidx,  // [2][N_EDGES]
    const float*          __restrict__ ea,    // [N_EDGES][3]
    const float*          __restrict__ W1,    // [131][64]
    const float*          __restrict__ b1,    // [64]
    unsigned int*         __restrict__ hsum,  // [N_NODES][32] packed-f16 pairs
    float*                __restrict__ cnt)   // [N_NODES] masked-edge counts
{
    __shared__ __align__(16) unsigned short W1T[64][136];   // [n][k] k<128 bf16; k=128..135: float4 tail
    __shared__ float eas[128][3];
    __shared__ int   dstm[128];   // dst | 0x80000000 if masked-in; 0 if masked-out
    __shared__ int   srcs[128];   // src (0 if masked-out)

    const int tid  = threadIdx.x;
    const int wave = tid >> 6;
    const int lane = tid & 63;
    const int q    = lane >> 4;   // quad 0..3
    const int m16  = lane & 15;

    // ---- stage W1 once per persistent block (fp32 -> bf16) ----
    for (int idx = tid; idx < 128 * 64; idx += 256) {
        int k = idx >> 6, n = idx & 63;
        W1T[n][k] = f2bf(W1[idx]);
    }
    if (tid < 64) {
        float4 tl;
        tl.x = W1[128 * 64 + tid];
        tl.y = W1[129 * 64 + tid];
        tl.z = W1[130 * 64 + tid];
        tl.w = b1[tid];
        *reinterpret_cast<float4*>(&W1T[tid][128]) = tl;   // row*272+256: 16B aligned
    }
    __syncthreads();   // the ONLY block barrier

    const int ebase = wave * 32;

    for (int t = blockIdx.x; t < N_TILES; t += gridDim.x) {
        // ---- per-wave staging: lanes 0..31 stage this wave's 32 edges ----
        if (lane < 32) {
            int e  = t * TILE + ebase + lane;
            int el = ebase + lane;
            int s = eidx[e];
            int d = eidx[N_EDGES + e];
            float a0 = ea[e * 3 + 0];
            float a1 = ea[e * 3 + 1];
            float a2 = ea[e * 3 + 2];
            eas[el][0] = a0; eas[el][1] = a1; eas[el][2] = a2;
            int ntc = ntype[s];   // 1-byte type, L2-resident table
            bool mk = (ntc == 0) ? (a0 < 0.5f) : ((ntc == 1) ? (a0 < 0.3f) : true);
            dstm[el] = mk ? (int)(0x80000000u | (unsigned)d) : 0;
            srcs[el] = mk ? s : 0;   // masked-out: gather node 0 (L1-hot)
            if (mk) unsafeAtomicAdd(&cnt[d], 1.0f);
        }

        // ---- acc init: b1 + ea @ W1[128:131] (fp32 VALU) ----
        f32x4 acc1[2][4];
#pragma unroll
        for (int mt = 0; mt < 2; ++mt) {
            float e0[4], e1[4], e2[4];
#pragma unroll
            for (int r = 0; r < 4; ++r) {
                int el = ebase + mt * 16 + q * 4 + r;   // C-layout row
                e0[r] = eas[el][0]; e1[r] = eas[el][1]; e2[r] = eas[el][2];
            }
#pragma unroll
            for (int nt = 0; nt < 4; ++nt) {
                int n = nt * 16 + m16;                  // C-layout col
                float4 wt = *reinterpret_cast<const float4*>(&W1T[n][128]);
#pragma unroll
                for (int r = 0; r < 4; ++r)
                    acc1[mt][nt][r] = wt.w + e0[r] * wt.x + e1[r] * wt.y + e2[r] * wt.z;
            }
        }

        // K=128 over [x_dst (kc 0,1) | x_src (kc 2,3)], A-frags from global bf16
#pragma unroll
        for (int kc = 0; kc < 4; ++kc) {
            bf16x8 af[2];
#pragma unroll
            for (int mt = 0; mt < 2; ++mt) {
                int el = ebase + mt * 16 + m16;         // A-layout row m=lane&15
                int dm = dstm[el];
                int node = (kc < 2) ? (dm & 0x7FFFFFFF) : srcs[el];
                af[mt] = *reinterpret_cast<const bf16x8*>(
                    xb + (size_t)node * IN_CH + (kc & 1) * 32 + q * 8);
            }
            __builtin_amdgcn_s_setprio(1);
#pragma unroll
            for (int nt = 0; nt < 4; ++nt) {
                bf16x8 bfr = *reinterpret_cast<const bf16x8*>(
                    &W1T[nt * 16 + m16][kc * 32 + q * 8]);
                acc1[0][nt] = __builtin_amdgcn_mfma_f32_16x16x32_bf16(af[0], bfr, acc1[0][nt], 0, 0, 0);
                acc1[1][nt] = __builtin_amdgcn_mfma_f32_16x16x32_bf16(af[1], bfr, acc1[1][nt], 0, 0, 0);
            }
            __builtin_amdgcn_s_setprio(0);
        }

        // ---- epilogue: masked relu(h) -> packed fp16 atomics, zero-skip ----
#pragma unroll
        for (int mt = 0; mt < 2; ++mt) {
#pragma unroll
            for (int r = 0; r < 4; ++r) {
                int el = ebase + mt * 16 + q * 4 + r;   // C-layout row
                int dm = dstm[el];
                if (dm < 0) {   // masked-in
                    unsigned int* hbase = hsum + (size_t)(dm & 0x7FFFFFFF) * 32;
                    float v0 = acc1[mt][0][r]; v0 = v0 > 0.f ? v0 : 0.f;
                    float v1 = acc1[mt][1][r]; v1 = v1 > 0.f ? v1 : 0.f;
                    float v2 = acc1[mt][2][r]; v2 = v2 > 0.f ? v2 : 0.f;
                    float v3 = acc1[mt][3][r]; v3 = v3 > 0.f ? v3 : 0.f;
                    if (v0 + v1 > 0.f) {   // pair (m16, m16+16) -> dword m16
                        f16x2 p01 = {(_Float16)v0, (_Float16)v1};
                        atomic_pk_add_f16(hbase + m16, p01);
                    }
                    if (v2 + v3 > 0.f) {   // pair (m16+32, m16+48) -> dword 16+m16
                        f16x2 p23 = {(_Float16)v2, (_Float16)v3};
                        atomic_pk_add_f16(hbase + 16 + m16, p23);
                    }
                }
            }
        }
    }
}

// Node kernel (MFMA): out[n] = relu(hsum[n] @ W2 + cnt[n]*b2).
// hsum is fp16 in permuted channel order pi(p); W2's rows are staged with the
// same permutation so the GEMM is oblivious to it.
__global__ __launch_bounds__(256, 4) void gnn_node_out(
    const _Float16* __restrict__ hsum,  // [N_NODES][64] fp16, permuted channels
    const float*    __restrict__ cnt,   // [N_NODES]
    const float*    __restrict__ W2,    // [64][128]
    const float*    __restrict__ b2,    // [128]
    float*          __restrict__ out)   // [N_NODES][128]
{
    __shared__ __align__(16) unsigned short W2T[128][72];  // W2T[n][p]=W2[pi(p)][n]
    __shared__ float b2s[128];

    const int tid  = threadIdx.x;
    const int wave = tid >> 6;
    const int lane = tid & 63;
    const int q    = lane >> 4;
    const int m16  = lane & 15;

    for (int idx = tid; idx < 64 * 128; idx += 256) {
        int p = idx >> 7, n = idx & 127;
        // pi(p): dword d=p>>1, half e=p&1; d<16 -> ch d+16e; d>=16 -> ch d+16+16e
        int ch = (p >> 1) + 16 * (p & 1) + ((p >= 32) ? 16 : 0);
        W2T[n][p] = f2bf(W2[ch * 128 + n]);
    }
    if (tid < 128) b2s[tid] = b2[tid];
    __syncthreads();

    const int nodeBase = (blockIdx.x * 4 + wave) * 32;
    if (nodeBase >= N_NODES) return;   // tail waves (no barriers below)

    f32x4 acc[2][8];
#pragma unroll
    for (int mt = 0; mt < 2; ++mt)
#pragma unroll
        for (int nt = 0; nt < 8; ++nt)
            acc[mt][nt] = (f32x4){0.0f, 0.0f, 0.0f, 0.0f};

#pragma unroll
    for (int kc = 0; kc < 2; ++kc) {
        bf16x8 af[2];
#pragma unroll
        for (int mt = 0; mt < 2; ++mt) {
            int node = nodeBase + mt * 16 + m16;       // A-layout row
            if (node >= N_NODES) node = N_NODES - 1;   // clamp; rows unused
            f16x8 h = *reinterpret_cast<const f16x8*>(
                hsum + (size_t)node * HID_CH + kc * 32 + q * 8);
            union { bf16x8 v; unsigned short u[8]; } rr;
#pragma unroll
            for (int j = 0; j < 8; ++j) rr.u[j] = f2bf((float)h[j]);
            af[mt] = rr.v;
        }
#pragma unroll
        for (int nt = 0; nt < 8; ++nt) {
            bf16x8 bfr = *reinterpret_cast<const bf16x8*>(
                &W2T[nt * 16 + m16][kc * 32 + q * 8]);
            acc[0][nt] = __builtin_amdgcn_mfma_f32_16x16x32_bf16(af[0], bfr, acc[0][nt], 0, 0, 0);
            acc[1][nt] = __builtin_amdgcn_mfma_f32_16x16x32_bf16(af[1], bfr, acc[1][nt], 0, 0, 0);
        }
    }

    // epilogue: + cnt*b2, relu, store (C-layout: row=q*4+r, col=nt*16+m16)
#pragma unroll
    for (int mt = 0; mt < 2; ++mt) {
        float cc[4]; int nn[4];
#pragma unroll
        for (int r = 0; r < 4; ++r) {
            nn[r] = nodeBase + mt * 16 + q * 4 + r;
            cc[r] = (nn[r] < N_NODES) ? cnt[nn[r]] : 0.0f;
        }
#pragma unroll
        for (int nt = 0; nt < 8; ++nt) {
            int col = nt * 16 + m16;
            float bb = b2s[col];
#pragma unroll
            for (int r = 0; r < 4; ++r) {
                if (nn[r] < N_NODES) {
                    float v = acc[mt][nt][r] + cc[r] * bb;
                    out[(size_t)nn[r] * OUT_CH + col] = v > 0.0f ? v : 0.0f;
                }
            }
        }
    }
}

extern "C" void kernel_launch(void* const* d_in, const int* in_sizes, int n_in,
                              void* d_out, int out_size, void* d_ws, size_t ws_size,
                              hipStream_t stream) {
    const float* x  = (const float*)d_in[0];
    const int*   ei = (const int*)d_in[1];
    const float* ea = (const float*)d_in[2];
    const float* W1 = (const float*)d_in[3];
    const float* b1 = (const float*)d_in[4];
    const float* W2 = (const float*)d_in[5];
    const float* b2 = (const float*)d_in[6];
    float* out = (float*)d_out;

    // ws layout: [hsum fp16 12.8MB][cnt 0.4MB][xb bf16 12.8MB][ntype 0.1MB]
    char* wsb = (char*)d_ws;
    unsigned int*   hsum  = (unsigned int*)wsb;                   // packed pairs
    float*          cnt   = (float*)(wsb + 12800000);
    unsigned short* xb    = (unsigned short*)(wsb + 13200000);
    unsigned char*  ntype = (unsigned char*)(wsb + 26000000);

    // fused prep: x->bf16 + node-type table + zero hsum/cnt
    gnn_prep<<<(2425000 + 255) / 256, 256, 0, stream>>>(
        x, xb, ntype, (uint4*)hsum, (float4*)cnt);

    // 2048 blocks, barrier-free persistent loop (VGPR ~60 -> HW can co-schedule
    // up to 8 blocks/CU with 19968B LDS)
    gnn_edge_hidden<<<2048, 256, 0, stream>>>(ntype, xb, ei, ea, W1, b1, hsum, cnt);

    // node-level layer 2 + relu via MFMA: 128 nodes/block, 782 blocks
    gnn_node_out<<<(N_NODES + 127) / 128, 256, 0, stream>>>(
        (const _Float16*)hsum, cnt, W2, b2, out);
}

// Round 4
// 271.911 us; speedup vs baseline: 2.1217x; 1.1877x over previous
//
#include <hip/hip_runtime.h>

#define N_NODES 100000
#define N_EDGES 1600000
#define IN_CH   64
#define HID_CH  64
#define OUT_CH  128
#define TILE    128
#define N_TILES (N_EDGES / TILE)   // 12500 exactly

typedef __attribute__((ext_vector_type(8))) __bf16    bf16x8;
typedef __attribute__((ext_vector_type(4))) float     f32x4;
typedef __attribute__((ext_vector_type(2))) _Float16  f16x2;
typedef __attribute__((ext_vector_type(8))) _Float16  f16x8;

__device__ __forceinline__ unsigned short f2bf(float f) {
    union { float f; unsigned int i; } c;
    c.f = f;
    unsigned int u = c.i;
    unsigned int r = (u + 0x7FFFu + ((u >> 16) & 1u)) >> 16;   // RNE
    return (unsigned short)r;
}

// packed fp16 atomic add (global_atomic_pk_add_f16, gfx90a+)
__device__ __forceinline__ void atomic_pk_add_f16(unsigned int* addr, f16x2 val) {
    typedef __attribute__((address_space(1))) f16x2 gf16x2;
    __builtin_amdgcn_global_atomic_fadd_v2f16((gf16x2*)(void*)addr, val);
}

// fused prep: x fp32->bf16 convert + node-type byte table + zero hsum/cnt.
__global__ void gnn_prep(const float* __restrict__ xf,
                         unsigned short* __restrict__ xb,
                         unsigned char* __restrict__ ntype,  // [N_NODES]
                         uint4* __restrict__ hz,      // hsum as uint4 (800k)
                         float4* __restrict__ cz) {   // cnt  as float4 (25k)
    int i = blockIdx.x * blockDim.x + threadIdx.x;
    if (i < 1600000) {
        float4 v = reinterpret_cast<const float4*>(xf)[i];
        ushort4 o;
        o.x = f2bf(v.x); o.y = f2bf(v.y); o.z = f2bf(v.z); o.w = f2bf(v.w);
        reinterpret_cast<ushort4*>(xb)[i] = o;
        if ((i & 15) == 0) {   // this vec4 holds cols 0..3 of node i/16
            int n = i >> 4;
            ntype[n] = (v.x == 0.0f) ? 0 : ((v.x == 1.0f) ? 1 : 2);
        }
    } else if (i < 2400000) {
        hz[i - 1600000] = (uint4){0u, 0u, 0u, 0u};
    } else if (i < 2425000) {
        cz[i - 2400000] = (float4){0.f, 0.f, 0.f, 0.f};
    }
}

// Edge kernel: h_e = relu([x_dst|x_src|ea] @ W1 + b1); masked scatter of the
// 64-ch hidden into hsum[dst] as PACKED fp16 atomics (2 ch/dword), zero-skip.
//
// Schedule = round-0's two-barrier lockstep (known-good 161us). Round-2's
// barrier-free variant thrashed L2 (FETCH 162->385MB, WRITE 150->238MB):
// the barriers phase-separate the gather working set from the atomic RMW
// working set in the 4MB XCD L2. KEEP THE BARRIERS.
//
// Data layout = round-2's LDS diet (19968B): W1 tail folded into W1T cols
// 128..135 as float4 {W1[128][n],W1[129][n],W1[130][n],b1[n]}; mask packed
// into dstm sign bit. 19968B <= 20480 -> 8 blocks/CU when VGPR<=64.
//
// Masked-out edges (~40%) redirect both xb gathers to node 0 (L1-hot); their
// MFMA rows are discarded in the epilogue anyway.
__global__ __launch_bounds__(256, 4) void gnn_edge_hidden(
    const unsigned char*  __restrict__ ntype, // [N_NODES] node type 0/1/2
    const unsigned short* __restrict__ xb,    // [N_NODES][64] bf16 bits
    const int*            __restrict__ eidx,  // [2][N_EDGES]
    const float*          __restrict__ ea,    // [N_EDGES][3]
    const float*          __restrict__ W1,    // [131][64]
    const float*          __restrict__ b1,    // [64]
    unsigned int*         __restrict__ hsum,  // [N_NODES][32] packed-f16 pairs
    float*                __restrict__ cnt)   // [N_NODES] masked-edge counts
{
    __shared__ __align__(16) unsigned short W1T[64][136];   // [n][k] k<128 bf16; k=128..135: float4 tail
    __shared__ float eas[128][3];
    __shared__ int   dstm[128];   // dst | 0x80000000 if masked-in; 0 if masked-out
    __shared__ int   srcs[128];   // src (0 if masked-out)

    const int tid  = threadIdx.x;
    const int wave = tid >> 6;
    const int lane = tid & 63;
    const int q    = lane >> 4;   // quad 0..3
    const int m16  = lane & 15;

    // ---- stage W1 once per persistent block (fp32 -> bf16) ----
    for (int idx = tid; idx < 128 * 64; idx += 256) {
        int k = idx >> 6, n = idx & 63;
        W1T[n][k] = f2bf(W1[idx]);
    }
    if (tid < 64) {
        float4 tl;
        tl.x = W1[128 * 64 + tid];
        tl.y = W1[129 * 64 + tid];
        tl.z = W1[130 * 64 + tid];
        tl.w = b1[tid];
        *reinterpret_cast<float4*>(&W1T[tid][128]) = tl;   // row*272+256: 16B aligned
    }

    for (int t = blockIdx.x; t < N_TILES; t += gridDim.x) {
        __syncthreads();   // covers weight staging (1st iter) + LDS WAR reuse
        if (tid < 128) {
            int e = t * TILE + tid;
            int s = eidx[e];
            int d = eidx[N_EDGES + e];
            float a0 = ea[e * 3 + 0];
            float a1 = ea[e * 3 + 1];
            float a2 = ea[e * 3 + 2];
            eas[tid][0] = a0; eas[tid][1] = a1; eas[tid][2] = a2;
            int ntc = ntype[s];   // 1-byte type, L2-resident table
            bool mk = (ntc == 0) ? (a0 < 0.5f) : ((ntc == 1) ? (a0 < 0.3f) : true);
            dstm[tid] = mk ? (int)(0x80000000u | (unsigned)d) : 0;
            srcs[tid] = mk ? s : 0;   // masked-out: gather node 0 (L1-hot)
            if (mk) unsafeAtomicAdd(&cnt[d], 1.0f);
        }
        __syncthreads();

        const int ebase = wave * 32;

        // ---- acc init: b1 + ea @ W1[128:131] (fp32 VALU) ----
        f32x4 acc1[2][4];
#pragma unroll
        for (int mt = 0; mt < 2; ++mt) {
            float e0[4], e1[4], e2[4];
#pragma unroll
            for (int r = 0; r < 4; ++r) {
                int el = ebase + mt * 16 + q * 4 + r;   // C-layout row
                e0[r] = eas[el][0]; e1[r] = eas[el][1]; e2[r] = eas[el][2];
            }
#pragma unroll
            for (int nt = 0; nt < 4; ++nt) {
                int n = nt * 16 + m16;                  // C-layout col
                float4 wt = *reinterpret_cast<const float4*>(&W1T[n][128]);
#pragma unroll
                for (int r = 0; r < 4; ++r)
                    acc1[mt][nt][r] = wt.w + e0[r] * wt.x + e1[r] * wt.y + e2[r] * wt.z;
            }
        }

        // K=128 over [x_dst (kc 0,1) | x_src (kc 2,3)], A-frags from global bf16
#pragma unroll
        for (int kc = 0; kc < 4; ++kc) {
            bf16x8 af[2];
#pragma unroll
            for (int mt = 0; mt < 2; ++mt) {
                int el = ebase + mt * 16 + m16;         // A-layout row m=lane&15
                int dm = dstm[el];
                int node = (kc < 2) ? (dm & 0x7FFFFFFF) : srcs[el];
                af[mt] = *reinterpret_cast<const bf16x8*>(
                    xb + (size_t)node * IN_CH + (kc & 1) * 32 + q * 8);
            }
#pragma unroll
            for (int nt = 0; nt < 4; ++nt) {
                bf16x8 bfr = *reinterpret_cast<const bf16x8*>(
                    &W1T[nt * 16 + m16][kc * 32 + q * 8]);
                acc1[0][nt] = __builtin_amdgcn_mfma_f32_16x16x32_bf16(af[0], bfr, acc1[0][nt], 0, 0, 0);
                acc1[1][nt] = __builtin_amdgcn_mfma_f32_16x16x32_bf16(af[1], bfr, acc1[1][nt], 0, 0, 0);
            }
        }

        // ---- epilogue: masked relu(h) -> packed fp16 atomics, zero-skip ----
#pragma unroll
        for (int mt = 0; mt < 2; ++mt) {
#pragma unroll
            for (int r = 0; r < 4; ++r) {
                int el = ebase + mt * 16 + q * 4 + r;   // C-layout row
                int dm = dstm[el];
                if (dm < 0) {   // masked-in
                    unsigned int* hbase = hsum + (size_t)(dm & 0x7FFFFFFF) * 32;
                    float v0 = acc1[mt][0][r]; v0 = v0 > 0.f ? v0 : 0.f;
                    float v1 = acc1[mt][1][r]; v1 = v1 > 0.f ? v1 : 0.f;
                    float v2 = acc1[mt][2][r]; v2 = v2 > 0.f ? v2 : 0.f;
                    float v3 = acc1[mt][3][r]; v3 = v3 > 0.f ? v3 : 0.f;
                    if (v0 + v1 > 0.f) {   // pair (m16, m16+16) -> dword m16
                        f16x2 p01 = {(_Float16)v0, (_Float16)v1};
                        atomic_pk_add_f16(hbase + m16, p01);
                    }
                    if (v2 + v3 > 0.f) {   // pair (m16+32, m16+48) -> dword 16+m16
                        f16x2 p23 = {(_Float16)v2, (_Float16)v3};
                        atomic_pk_add_f16(hbase + 16 + m16, p23);
                    }
                }
            }
        }
    }
}

// Node kernel (MFMA): out[n] = relu(hsum[n] @ W2 + cnt[n]*b2).
// hsum is fp16 in permuted channel order pi(p); W2's rows are staged with the
// same permutation so the GEMM is oblivious to it.
// hsum/cnt loads are issued BEFORE the W2T staging loop so their HBM latency
// hides under the staging work instead of serializing after __syncthreads.
__global__ __launch_bounds__(256, 4) void gnn_node_out(
    const _Float16* __restrict__ hsum,  // [N_NODES][64] fp16, permuted channels
    const float*    __restrict__ cnt,   // [N_NODES]
    const float*    __restrict__ W2,    // [64][128]
    const float*    __restrict__ b2,    // [128]
    float*          __restrict__ out)   // [N_NODES][128]
{
    __shared__ __align__(16) unsigned short W2T[128][72];  // W2T[n][p]=W2[pi(p)][n]
    __shared__ float b2s[128];

    const int tid  = threadIdx.x;
    const int wave = tid >> 6;
    const int lane = tid & 63;
    const int q    = lane >> 4;
    const int m16  = lane & 15;

    const int nodeBase = (blockIdx.x * 4 + wave) * 32;

    // ---- prefetch this wave's hsum rows + cnt (independent of LDS) ----
    f16x8 hpre[2][2];
    float cc[2][4];
#pragma unroll
    for (int kc = 0; kc < 2; ++kc)
#pragma unroll
        for (int mt = 0; mt < 2; ++mt) {
            int node = nodeBase + mt * 16 + m16;       // A-layout row
            if (node >= N_NODES) node = N_NODES - 1;   // clamp; rows unused
            hpre[kc][mt] = *reinterpret_cast<const f16x8*>(
                hsum + (size_t)node * HID_CH + kc * 32 + q * 8);
        }
#pragma unroll
    for (int mt = 0; mt < 2; ++mt)
#pragma unroll
        for (int r = 0; r < 4; ++r) {
            int n = nodeBase + mt * 16 + q * 4 + r;
            cc[mt][r] = (n < N_NODES) ? cnt[n] : 0.0f;
        }

    // ---- stage W2 (transposed + channel-permuted, fp32 -> bf16) ----
    for (int idx = tid; idx < 64 * 128; idx += 256) {
        int p = idx >> 7, n = idx & 127;
        // pi(p): dword d=p>>1, half e=p&1; d<16 -> ch d+16e; d>=16 -> ch d+16+16e
        int ch = (p >> 1) + 16 * (p & 1) + ((p >= 32) ? 16 : 0);
        W2T[n][p] = f2bf(W2[ch * 128 + n]);
    }
    if (tid < 128) b2s[tid] = b2[tid];
    __syncthreads();

    if (nodeBase >= N_NODES) return;   // tail waves (no barriers below)

    f32x4 acc[2][8];
#pragma unroll
    for (int mt = 0; mt < 2; ++mt)
#pragma unroll
        for (int nt = 0; nt < 8; ++nt)
            acc[mt][nt] = (f32x4){0.0f, 0.0f, 0.0f, 0.0f};

#pragma unroll
    for (int kc = 0; kc < 2; ++kc) {
        bf16x8 af[2];
#pragma unroll
        for (int mt = 0; mt < 2; ++mt) {
            union { bf16x8 v; unsigned short u[8]; } rr;
#pragma unroll
            for (int j = 0; j < 8; ++j) rr.u[j] = f2bf((float)hpre[kc][mt][j]);
            af[mt] = rr.v;
        }
#pragma unroll
        for (int nt = 0; nt < 8; ++nt) {
            bf16x8 bfr = *reinterpret_cast<const bf16x8*>(
                &W2T[nt * 16 + m16][kc * 32 + q * 8]);
            acc[0][nt] = __builtin_amdgcn_mfma_f32_16x16x32_bf16(af[0], bfr, acc[0][nt], 0, 0, 0);
            acc[1][nt] = __builtin_amdgcn_mfma_f32_16x16x32_bf16(af[1], bfr, acc[1][nt], 0, 0, 0);
        }
    }

    // epilogue: + cnt*b2, relu, store (C-layout: row=q*4+r, col=nt*16+m16)
#pragma unroll
    for (int mt = 0; mt < 2; ++mt) {
        int nn[4];
#pragma unroll
        for (int r = 0; r < 4; ++r)
            nn[r] = nodeBase + mt * 16 + q * 4 + r;
#pragma unroll
        for (int nt = 0; nt < 8; ++nt) {
            int col = nt * 16 + m16;
            float bb = b2s[col];
#pragma unroll
            for (int r = 0; r < 4; ++r) {
                if (nn[r] < N_NODES) {
                    float v = acc[mt][nt][r] + cc[mt][r] * bb;
                    out[(size_t)nn[r] * OUT_CH + col] = v > 0.0f ? v : 0.0f;
                }
            }
        }
    }
}

extern "C" void kernel_launch(void* const* d_in, const int* in_sizes, int n_in,
                              void* d_out, int out_size, void* d_ws, size_t ws_size,
                              hipStream_t stream) {
    const float* x  = (const float*)d_in[0];
    const int*   ei = (const int*)d_in[1];
    const float* ea = (const float*)d_in[2];
    const float* W1 = (const float*)d_in[3];
    const float* b1 = (const float*)d_in[4];
    const float* W2 = (const float*)d_in[5];
    const float* b2 = (const float*)d_in[6];
    float* out = (float*)d_out;

    // ws layout: [hsum fp16 12.8MB][cnt 0.4MB][xb bf16 12.8MB][ntype 0.1MB]
    char* wsb = (char*)d_ws;
    unsigned int*   hsum  = (unsigned int*)wsb;                   // packed pairs
    float*          cnt   = (float*)(wsb + 12800000);
    unsigned short* xb    = (unsigned short*)(wsb + 13200000);
    unsigned char*  ntype = (unsigned char*)(wsb + 26000000);

    // fused prep: x->bf16 + node-type table + zero hsum/cnt
    gnn_prep<<<(2425000 + 255) / 256, 256, 0, stream>>>(
        x, xb, ntype, (uint4*)hsum, (float4*)cnt);

    // 2048 blocks: 19968B LDS + VGPR<=64 -> 8 blocks/CU, two-barrier lockstep
    gnn_edge_hidden<<<2048, 256, 0, stream>>>(ntype, xb, ei, ea, W1, b1, hsum, cnt);

    // node-level layer 2 + relu via MFMA: 128 nodes/block, 782 blocks
    gnn_node_out<<<(N_NODES + 127) / 128, 256, 0, stream>>>(
        (const _Float16*)hsum, cnt, W2, b2, out);
}